// Round 16
// baseline (60.687 us; speedup 1.0000x reference)
//
#include <hip/hip_runtime.h>

// STN forward, R16 = R15 slab tiling + LDS-conflict-free gather.
// Voxel ownership remapped to w-stride-32: thread owns w in {wt+32j},
// wt=tid&31 -> within one gather instruction lanes cover all 32 banks
// (~2-way, free) instead of 8 banks 8-way. Gather via ds_read2_b32:
// per voxel 2 addrs (d0/d1 plane), offsets (0,1)+(128,129) cover the
// 4 corner pairs. 16 read2s batched -> ONE lgkmcnt(0)+sched_barrier(0).
// IO is scalar per voxel but lane-contiguous (coalesced). R15 staging.

constexpr int B = 2, C = 2, D = 128, H = 128, W = 128;
constexpr int HW  = H * W;
constexpr int DHW = D * HW;
constexpr int TDd = 8, TDh = 8;              // tile: 8 x 8 x 128
constexpr int RD = 15, RH = 15;              // region extents (halo 3)
constexpr int CHF = RD * RH * W;             // 28,800 floats = 115,200 B
constexpr int CHG = CHF / 4;                 // 7,200 16B granules
constexpr int NT = 1024;
constexpr int NFULL = 7;                     // 7*1024 = 7168 granules
constexpr int TAILN = CHG - NFULL * NT;      // 32 tail granules
constexpr int ROWSTRIDE = W;                 // 128 dwords (fits read2 offset)
constexpr int PLANESTRIDE = RH * W;          // 1920 dwords
constexpr int PLANE_B = PLANESTRIDE * 4;     // 7680 B

typedef float v2f __attribute__((ext_vector_type(2)));

__device__ __forceinline__ void gload_lds16(const float* g, float* l) {
    __builtin_amdgcn_global_load_lds(
        (const __attribute__((address_space(1))) void*)g,
        (__attribute__((address_space(3))) void*)l, 16, 0, 0);
}

__global__ __launch_bounds__(NT) void stn_kernel(
    const float* __restrict__ image,
    const float* __restrict__ ddf,
    float* __restrict__ out)
{
    __shared__ float smem[CHF];              // 115,200 B

    // XCD-contiguous swizzle (512 blocks, 512%8==0 -> bijective)
    const int bid = blockIdx.x;
    const int cpx = gridDim.x >> 3;          // 64
    const int blk = (bid & 7) * cpx + (bid >> 3);

    const int b   = blk >> 8;                // 256 tiles per batch (16d x 16h)
    const int tb  = blk & 255;
    const int t0d = (tb >> 4) * TDd, t0h = (tb & 15) * TDh;
    const int lo_d = max(t0d - 3, 0), lo_h = max(t0h - 3, 0);
    const int hi_d = min(lo_d + RD - 1, D - 1);
    const int hi_h = min(lo_h + RH - 1, H - 1);
    const float* imgb = image + (size_t)b * C * DHW;
    const int tid = threadIdx.x;
    const unsigned lds0 =
        (unsigned)(uintptr_t)(__attribute__((address_space(3))) void*)&smem[0];

    // voxel ownership: d in {t0d+dl, t0d+dl+4}, h = t0h+hl, w in {wt+32j}
    const int dl = tid >> 8;                 // 0..3
    const int hl = (tid >> 5) & 7;           // 0..7
    const int wt = tid & 31;                 // 0..31
    const int d0_ = t0d + dl, h_ = t0h + hl;
    const int srow0 = d0_ * HW + h_ * W + wt;        // d-row 0 base (+32j)
    const int srow1 = srow0 + 4 * HW;                // d-row 1 base

    // ---- ddf loads FIRST: 24 scalar loads (lane-contiguous in w) ----
    const float* dp = ddf + (size_t)b * 3 * DHW;
    float vd[8], vh[8], vw[8];
#pragma unroll
    for (int r = 0; r < 2; ++r) {
        int base = r ? srow1 : srow0;
#pragma unroll
        for (int j = 0; j < 4; ++j) {
            int si = base + 32 * j;
            vd[r * 4 + j] = dp[si];
            vh[r * 4 + j] = dp[DHW + si];
            vw[r * 4 + j] = dp[2 * DHW + si];
        }
    }
    asm volatile("" ::: "memory");

    // granule g -> global offset (full-W rows, h-adjacent => contiguous slabs)
    auto gsrc_off = [&](int g) {
        int row = g >> 5;                    // 32 granules per row
        int rw  = (g & 31) << 2;
        int rd  = row / RH;
        int rh  = row - rd * RH;
        return min(lo_d + rd, D - 1) * HW + min(lo_h + rh, H - 1) * W + rw;
    };

    auto issue_stage = [&](const float* src) {
#pragma unroll
        for (int i = 0; i < NFULL; ++i) {
            int g = tid + i * NT;                       // < 7168 < CHG
            gload_lds16(src + gsrc_off(g), &smem[g * 4]);
        }
        if (tid < TAILN) {
            int g = tid + NFULL * NT;                   // 7168..7199
            float4 v = *reinterpret_cast<const float4*>(src + gsrc_off(g));
            *reinterpret_cast<float4*>(&smem[g * 4]) = v;
        }
    };

    issue_stage(imgb);                                  // ch0 in flight
    asm volatile("" ::: "memory");

    // clamped coords, 8 voxels (24 VGPR, persisted across both passes)
    float cdk[8], chk[8], cwk[8];
#pragma unroll
    for (int r = 0; r < 2; ++r) {
#pragma unroll
        for (int j = 0; j < 4; ++j) {
            int v = r * 4 + j;
            cdk[v] = fminf(fmaxf((float)(d0_ + 4 * r) + vd[v], 0.0f), (float)(D - 1));
            chk[v] = fminf(fmaxf((float)h_ + vh[v], 0.0f), (float)(H - 1));
            cwk[v] = fminf(fmaxf((float)(wt + 32 * j) + vw[v], 0.0f), (float)(W - 1));
        }
    }

    // one pass: 2 batches of 4 voxels; per batch 16 ds_read2 -> one wait.
    auto do_pass = [&](const float* gimg, float* obase) {
#pragma unroll
        for (int r = 0; r < 2; ++r) {
            unsigned a0[4];
            float W00[4], W01[4], W10[4], W11[4], GD[4], FD[4];
            int fb = 0;
#pragma unroll
            for (int k = 0; k < 4; ++k) {
                int v = r * 4 + k;
                float cd = cdk[v], ch = chk[v], cw = cwk[v];
                float d0f = floorf(cd), h0f = floorf(ch), w0f = floorf(cw);
                float fd = cd - d0f, fh = ch - h0f, fw = cw - w0f;
                int d0 = (int)d0f, h0 = (int)h0f, w0 = (int)w0f;
                bool bad = (d0 < lo_d) | (d0 + 1 > hi_d)
                         | (h0 < lo_h) | (h0 + 1 > hi_h)
                         | (w0 >= W - 1);
                fb |= (int)bad << k;
                float gh = 1.0f - fh, gw = 1.0f - fw;
                W00[k] = gh * gw; W01[k] = gh * fw;
                W10[k] = fh * gw; W11[k] = fh * fw;
                GD[k] = 1.0f - fd; FD[k] = fd;
                int i00 = ((d0 - lo_d) * RH + (h0 - lo_h)) * ROWSTRIDE + w0;
                a0[k] = lds0 + (unsigned)(i00 * 4);
            }
            v2f r00[4], r01[4], r10[4], r11[4];
#pragma unroll
            for (int k = 0; k < 4; ++k) {
                unsigned a1 = a0[k] + PLANE_B;
                asm volatile("ds_read2_b32 %0, %1 offset0:0 offset1:1"
                             : "=v"(r00[k]) : "v"(a0[k]));
                asm volatile("ds_read2_b32 %0, %1 offset0:128 offset1:129"
                             : "=v"(r01[k]) : "v"(a0[k]));
                asm volatile("ds_read2_b32 %0, %1 offset0:0 offset1:1"
                             : "=v"(r10[k]) : "v"(a1));
                asm volatile("ds_read2_b32 %0, %1 offset0:128 offset1:129"
                             : "=v"(r11[k]) : "v"(a1));
            }
            asm volatile("s_waitcnt lgkmcnt(0)" ::: "memory");
            __builtin_amdgcn_sched_barrier(0);

            float acc[4];
#pragma unroll
            for (int k = 0; k < 4; ++k) {
                float p0 = r00[k].x * W00[k] + r00[k].y * W01[k]
                         + r01[k].x * W10[k] + r01[k].y * W11[k];
                float p1 = r10[k].x * W00[k] + r10[k].y * W01[k]
                         + r11[k].x * W10[k] + r11[k].y * W11[k];
                acc[k] = GD[k] * p0 + FD[k] * p1;
            }
            if (fb) {                                   // rare exact fixup
#pragma unroll
                for (int k = 0; k < 4; ++k) {
                    if (fb & (1 << k)) {
                        int v = r * 4 + k;
                        float cd = cdk[v], ch = chk[v], cw = cwk[v];
                        float d0f = floorf(cd), h0f = floorf(ch), w0f = floorf(cw);
                        float fd = cd - d0f, fh = ch - h0f, fw = cw - w0f;
                        int d0 = (int)d0f, h0 = (int)h0f, w0 = (int)w0f;
                        int d1 = min(d0 + 1, D - 1);
                        int h1 = min(h0 + 1, H - 1);
                        int w1 = min(w0 + 1, W - 1);
                        float gd = 1.0f - fd, gh = 1.0f - fh, gw = 1.0f - fw;
                        float w00 = gh * gw, w01 = gh * fw, w10 = fh * gw, w11 = fh * fw;
                        int o00 = d0 * HW + h0 * W, o01 = d0 * HW + h1 * W;
                        int o10 = d1 * HW + h0 * W, o11 = d1 * HW + h1 * W;
                        float q0 = gimg[o00 + w0] * w00 + gimg[o00 + w1] * w01
                                 + gimg[o01 + w0] * w10 + gimg[o01 + w1] * w11;
                        float q1 = gimg[o10 + w0] * w00 + gimg[o10 + w1] * w01
                                 + gimg[o11 + w0] * w10 + gimg[o11 + w1] * w11;
                        acc[k] = gd * q0 + fd * q1;
                    }
                }
            }
            int base = (r ? srow1 : srow0);
#pragma unroll
            for (int k = 0; k < 4; ++k)
                obase[base + 32 * k] = acc[k];
        }
    };

    // ---- pass 0 ----
    asm volatile("s_waitcnt vmcnt(0) lgkmcnt(0)" ::: "memory");
    __builtin_amdgcn_s_barrier();
    do_pass(imgb, out + ((size_t)b * C + 0) * DHW);

    __builtin_amdgcn_s_barrier();                       // ch0 reads done
    asm volatile("" ::: "memory");

    // ---- pass 1 ----
    issue_stage(imgb + DHW);
    asm volatile("s_waitcnt vmcnt(0) lgkmcnt(0)" ::: "memory");
    __builtin_amdgcn_s_barrier();
    do_pass(imgb + DHW, out + ((size_t)b * C + 1) * DHW);
}

extern "C" void kernel_launch(void* const* d_in, const int* in_sizes, int n_in,
                              void* d_out, int out_size, void* d_ws, size_t ws_size,
                              hipStream_t stream) {
    const float* image = (const float*)d_in[0];
    const float* ddf   = (const float*)d_in[1];
    float* out = (float*)d_out;

    int grid = B * 256;   // 16x16 tiles of 8x8x128 per batch = 512 blocks
    stn_kernel<<<grid, NT, 0, stream>>>(image, ddf, out);
}

// Round 17
// 47.323 us; speedup vs baseline: 1.2824x; 1.2824x over previous
//
#include <hip/hip_runtime.h>

// STN forward, R17: R15 slab staging + persistent-block counted-vmcnt
// double-buffer pipeline. Tile 4x4x128, region 11x11x128 (61,952B) padded
// to 64KB/buffer -> uniform 4 gload_lds/thread (no tail). One block per CU
// (grid=256), 8 h-consecutive tiles each (halo overlap -> L2 reuse), 16
// phases; per phase: barrier -> issue next stage -> vmcnt(4|7) (never 0
// mid-loop) -> barrier -> gather+store. ddf prefetched one phase ahead,
// issued BEFORE the stage so the compiler's coord-wait is vmcnt(4).
// IO stays float2-coalesced (R16 lesson: scalar IO tripled write traffic).

constexpr int B = 2, C = 2, D = 128, H = 128, W = 128;
constexpr int HW  = H * W;
constexpr int DHW = D * HW;
constexpr int RD = 11, RH = 11;              // region extents (halo 3)
constexpr int CHG = RD * RH * 32;            // 3872 16B granules (61,952B)
constexpr int BUFG = 4096;                   // padded: 4 uniform rounds
constexpr int NT = 1024;
constexpr int TPB = 8;                       // h-consecutive tiles per block
constexpr int RS = 128;                      // LDS row stride (dwords)
constexpr int PS = RH * 128;                 // LDS plane stride (dwords)

__device__ __forceinline__ void gload_lds16(const float* g, float* l) {
    __builtin_amdgcn_global_load_lds(
        (const __attribute__((address_space(1))) void*)g,
        (__attribute__((address_space(3))) void*)l, 16, 0, 0);
}

__global__ __launch_bounds__(NT) void stn_kernel(
    const float* __restrict__ image,
    const float* __restrict__ ddf,
    float* __restrict__ out)
{
    __shared__ float smem[2 * BUFG * 4];     // 131,072 B -> 1 block/CU

    // XCD-contiguous block mapping: 32 consecutive logical blocks
    // (8 d-tiles x 4 h-groups) per XCD.
    const int bid = blockIdx.x;              // 256
    const int L   = (bid & 7) * 32 + (bid >> 3);
    const int b   = L >> 7, dti = (L >> 2) & 31, hg = L & 3;
    const int t0d = dti * 4;
    const int lo_d = max(t0d - 3, 0);
    const int hi_d = min(lo_d + RD - 1, D - 1);
    const float* imgb = image + (size_t)b * C * DHW;
    const float* dp   = ddf + (size_t)b * 3 * DHW;
    float* outb = out + (size_t)b * C * DHW;

    const int tid = threadIdx.x;
    const int dl = tid >> 8, hl = (tid >> 6) & 3, wq = tid & 63;
    const int w2 = wq * 2;
    const int d_ = t0d + dl;

    // stage one channel region into dst buffer: uniform 4 gloads/thread
    auto issue_stage = [&](const float* src, int lo_h, float* dst) {
#pragma unroll
        for (int i = 0; i < 4; ++i) {
            int g  = tid + i * NT;                      // 0..4095
            int gs = min(g, CHG - 1);                   // clamp SOURCE only
            int row = gs >> 5;
            int rd = row / RH, rh = row - rd * RH;
            int off = min(lo_d + rd, D - 1) * HW + min(lo_h + rh, H - 1) * W
                    + ((gs & 31) << 2);
            gload_lds16(src + off, dst + g * 4);        // dest contiguous
        }
    };

    // gather 2 voxels (w2, w2+1) from LDS; rare exact global fixup; f2 store
    auto do_pass = [&](const float* sm, const float* gimg, float* optr,
                       int lo_h, int hi_h,
                       float cd0, float ch0c, float cw0,
                       float cd1, float ch1c, float cw1) {
        float acc[2];
        int fb = 0;
        const float cds[2] = {cd0, cd1};
        const float chs[2] = {ch0c, ch1c};
        const float cws[2] = {cw0, cw1};
#pragma unroll
        for (int k = 0; k < 2; ++k) {
            float cd = cds[k], ch = chs[k], cw = cws[k];
            float d0f = floorf(cd), h0f = floorf(ch), w0f = floorf(cw);
            float fd = cd - d0f, fh = ch - h0f, fw = cw - w0f;
            int d0 = (int)d0f, h0 = (int)h0f, w0 = (int)w0f;
            bool bad = (d0 < lo_d) | (d0 + 1 > hi_d)
                     | (h0 < lo_h) | (h0 + 1 > hi_h)
                     | (w0 >= W - 1);
            fb |= (int)bad << k;
            float gd = 1.0f - fd, gh = 1.0f - fh, gw = 1.0f - fw;
            float w00 = gh * gw, w01 = gh * fw, w10 = fh * gw, w11 = fh * fw;
            int i00 = ((d0 - lo_d) * RH + (h0 - lo_h)) * RS + w0;
            int i01 = i00 + RS;
            int i10 = i00 + PS;
            int i11 = i10 + RS;
            float p0 = sm[i00] * w00 + sm[i00 + 1] * w01
                     + sm[i01] * w10 + sm[i01 + 1] * w11;
            float p1 = sm[i10] * w00 + sm[i10 + 1] * w01
                     + sm[i11] * w10 + sm[i11 + 1] * w11;
            acc[k] = gd * p0 + fd * p1;                 // garbage if bad
        }
        if (fb) {                                       // rare exact fixup
#pragma unroll
            for (int k = 0; k < 2; ++k) {
                if (fb & (1 << k)) {
                    float cd = cds[k], ch = chs[k], cw = cws[k];
                    float d0f = floorf(cd), h0f = floorf(ch), w0f = floorf(cw);
                    float fd = cd - d0f, fh = ch - h0f, fw = cw - w0f;
                    int d0 = (int)d0f, h0 = (int)h0f, w0 = (int)w0f;
                    int d1 = min(d0 + 1, D - 1);
                    int h1 = min(h0 + 1, H - 1);
                    int w1 = min(w0 + 1, W - 1);
                    float gd = 1.0f - fd, gh = 1.0f - fh, gw = 1.0f - fw;
                    float w00 = gh * gw, w01 = gh * fw, w10 = fh * gw, w11 = fh * fw;
                    int o00 = d0 * HW + h0 * W, o01 = d0 * HW + h1 * W;
                    int o10 = d1 * HW + h0 * W, o11 = d1 * HW + h1 * W;
                    float q0 = gimg[o00 + w0] * w00 + gimg[o00 + w1] * w01
                             + gimg[o01 + w0] * w10 + gimg[o01 + w1] * w11;
                    float q1 = gimg[o10 + w0] * w00 + gimg[o10 + w1] * w01
                             + gimg[o11 + w0] * w10 + gimg[o11 + w1] * w11;
                    acc[k] = gd * q0 + fd * q1;
                }
            }
        }
        *reinterpret_cast<float2*>(optr) = make_float2(acc[0], acc[1]);
    };

    // ---- prologue: ddf(tile0) then stage(tile0 ch0 -> buf0) ----
    int t0h  = hg * 32;                      // (hg*8 + 0) * 4
    int lo_h = max(t0h - 3, 0);
    float2 vd, vh, vw;
    {
        int si = d_ * HW + (t0h + hl) * W + w2;
        vd = *reinterpret_cast<const float2*>(dp + si);
        vh = *reinterpret_cast<const float2*>(dp + DHW + si);
        vw = *reinterpret_cast<const float2*>(dp + 2 * DHW + si);
    }
    asm volatile("" ::: "memory");
    issue_stage(imgb, lo_h, &smem[0]);
    asm volatile("" ::: "memory");

#pragma unroll 1
    for (int i = 0; i < TPB; ++i) {
        const int hi_h = min(lo_h + RH - 1, H - 1);
        const int h_ = t0h + hl;
        const int sidx = d_ * HW + h_ * W + w2;

        // coords for this tile (compiler waits vmcnt(<=4) for ddf here)
        float cd0 = fminf(fmaxf((float)d_ + vd.x, 0.0f), (float)(D - 1));
        float cd1 = fminf(fmaxf((float)d_ + vd.y, 0.0f), (float)(D - 1));
        float chA = fminf(fmaxf((float)h_ + vh.x, 0.0f), (float)(H - 1));
        float chB = fminf(fmaxf((float)h_ + vh.y, 0.0f), (float)(H - 1));
        float cw0 = fminf(fmaxf((float)w2 + vw.x, 0.0f), (float)(W - 1));
        float cw1 = fminf(fmaxf((float)(w2 + 1) + vw.y, 0.0f), (float)(W - 1));

        // ---- phase ch0 ----
        __builtin_amdgcn_s_barrier();                   // buf1 free
        issue_stage(imgb + DHW, lo_h, &smem[BUFG * 4]); // ch1 -> buf1 (4)
        asm volatile("s_waitcnt vmcnt(4)" ::: "memory");// ch0 staged
        __builtin_amdgcn_s_barrier();
        do_pass(&smem[0], imgb, outb + sidx, lo_h, hi_h,
                cd0, chA, cw0, cd1, chB, cw1);

        // ---- phase ch1 ----
        __builtin_amdgcn_s_barrier();                   // buf0 free
        int n_t0h = t0h + 4;
        int n_lo_h = max(n_t0h - 3, 0);
        if (i < TPB - 1) {
            {   // ddf(tile i+1): 3 loads, issued BEFORE the stage
                int si = d_ * HW + (n_t0h + hl) * W + w2;
                vd = *reinterpret_cast<const float2*>(dp + si);
                vh = *reinterpret_cast<const float2*>(dp + DHW + si);
                vw = *reinterpret_cast<const float2*>(dp + 2 * DHW + si);
            }
            asm volatile("" ::: "memory");
            issue_stage(imgb, n_lo_h, &smem[0]);        // ch0(i+1) -> buf0 (4)
            asm volatile("s_waitcnt vmcnt(7)" ::: "memory");  // ch1 staged
        } else {
            asm volatile("s_waitcnt vmcnt(0)" ::: "memory");
        }
        __builtin_amdgcn_s_barrier();
        do_pass(&smem[BUFG * 4], imgb + DHW, outb + DHW + sidx, lo_h, hi_h,
                cd0, chA, cw0, cd1, chB, cw1);

        t0h = n_t0h; lo_h = n_lo_h;
    }
}

extern "C" void kernel_launch(void* const* d_in, const int* in_sizes, int n_in,
                              void* d_out, int out_size, void* d_ws, size_t ws_size,
                              hipStream_t stream) {
    const float* image = (const float*)d_in[0];
    const float* ddf   = (const float*)d_in[1];
    float* out = (float*)d_out;

    int grid = 256;   // persistent: 2 batches x 32 d-tiles x 4 h-groups
    stn_kernel<<<grid, NT, 0, stream>>>(image, ddf, out);
}

// Round 18
// 46.791 us; speedup vs baseline: 1.2970x; 1.0114x over previous
//
#include <hip/hip_runtime.h>

// STN forward, R18: channel-interleaved LDS => both channels in ONE pass.
// LDS layout [row=(rd*11+rh)][w=0..127][c=0..1] (row=1024B): the corner quad
// (w0,w1)x(c0,c1) is ONE ds_read2_b64 (offsets in 8B units; h+1 = +128,
// d+1 = +11264B via 2nd addr). Per voxel: 4 LDS instrs for both channels
// (was 16) and coord/weight/bounds VALU computed once (was twice).
// Staging reg-staged (interleave impossible via global_load_lds): 4 rounds
// of 2x global_load_dwordx4 -> 2x shuffled ds_write_b128. Tile 4x4x128,
// region 11x11x128x2 = 123,904B, one __syncthreads per block.

constexpr int B = 2, C = 2, D = 128, H = 128, W = 128;
constexpr int HW  = H * W;
constexpr int DHW = D * HW;
constexpr int RD = 11, RH = 11;              // region extents (halo 3)
constexpr int NROW = RD * RH;                // 121 rows
constexpr int LDSF = NROW * 256;             // 30,976 floats = 123,904 B
constexpr int NPAIR = NROW * 32;             // 3872 granule-pairs (32B each)
constexpr int NT = 1024;
constexpr int ROW_B = 1024;                  // bytes per (w,c) row
constexpr int PLANE_B = RH * ROW_B;          // 11264 B per d-plane

typedef float v4f __attribute__((ext_vector_type(4)));

__global__ __launch_bounds__(NT) void stn_kernel(
    const float* __restrict__ image,
    const float* __restrict__ ddf,
    float* __restrict__ out)
{
    __shared__ float smem[LDSF];

    // XCD-contiguous swizzle (2048 blocks, %8==0 -> bijective)
    const int bid = blockIdx.x;
    const int cpx = gridDim.x >> 3;          // 256
    const int blk = (bid & 7) * cpx + (bid >> 3);

    const int b   = blk >> 10;               // 1024 tiles per batch (32d x 32h)
    const int tb  = blk & 1023;
    const int t0d = (tb >> 5) * 4, t0h = (tb & 31) * 4;
    const int lo_d = max(t0d - 3, 0), lo_h = max(t0h - 3, 0);
    const int hi_d = min(lo_d + RD - 1, D - 1);
    const int hi_h = min(lo_h + RH - 1, H - 1);
    const float* imgb = image + (size_t)b * C * DHW;
    const int tid = threadIdx.x;
    const unsigned lds0 =
        (unsigned)(uintptr_t)(__attribute__((address_space(3))) void*)&smem[0];

    // voxels: (d_, h_, w2) and (d_, h_, w2+1)
    const int dd = tid >> 8, hh = (tid >> 6) & 3;
    const int w2 = (tid & 63) * 2;
    const int d_ = t0d + dd, h_ = t0h + hh;
    const int sidx = d_ * HW + h_ * W + w2;

    // ---- ddf loads (issue first) ----
    const float* dp = ddf + (size_t)b * 3 * DHW;
    float2 vd = *reinterpret_cast<const float2*>(dp + sidx);
    float2 vh = *reinterpret_cast<const float2*>(dp + DHW + sidx);
    float2 vw = *reinterpret_cast<const float2*>(dp + 2 * DHW + sidx);

    // ---- stage loads into regs (both channels), 4 rounds ----
    float4 sA[4], sB[4];
    int qv[4];
#pragma unroll
    for (int i = 0; i < 4; ++i) {
        int q = tid + i * NT;
        if (i == 3) q = (q < NPAIR) ? q : (tid - (NPAIR - 3 * NT)); // distinct dup
        qv[i] = q;
        int row = q >> 5, p4 = (q & 31) << 2;
        int rd = row / RH, rh = row - rd * RH;
        int off = min(lo_d + rd, D - 1) * HW + min(lo_h + rh, H - 1) * W + p4;
        sA[i] = *reinterpret_cast<const float4*>(imgb + off);
        sB[i] = *reinterpret_cast<const float4*>(imgb + DHW + off);
    }

    // coords (computed once, used for both channels)
    float cds[2], chs[2], cws[2];
    cds[0] = fminf(fmaxf((float)d_ + vd.x, 0.0f), (float)(D - 1));
    cds[1] = fminf(fmaxf((float)d_ + vd.y, 0.0f), (float)(D - 1));
    chs[0] = fminf(fmaxf((float)h_ + vh.x, 0.0f), (float)(H - 1));
    chs[1] = fminf(fmaxf((float)h_ + vh.y, 0.0f), (float)(H - 1));
    cws[0] = fminf(fmaxf((float)w2 + vw.x, 0.0f), (float)(W - 1));
    cws[1] = fminf(fmaxf((float)(w2 + 1) + vw.y, 0.0f), (float)(W - 1));

    // ---- interleaved LDS writes: [.. w0c0 w0c1 w1c0 w1c1 ..] ----
#pragma unroll
    for (int i = 0; i < 4; ++i) {
        float* dst = &smem[qv[i] * 8];
        *reinterpret_cast<float4*>(dst) =
            make_float4(sA[i].x, sB[i].x, sA[i].y, sB[i].y);
        *reinterpret_cast<float4*>(dst + 4) =
            make_float4(sA[i].z, sB[i].z, sA[i].w, sB[i].w);
    }
    __syncthreads();

    // ---- gather: per voxel 4x ds_read2_b64 (both channels) ----
    unsigned a0[2];
    float GW[2], FW[2], GH[2], FH[2], GD[2], FD[2];
    int fb = 0;
#pragma unroll
    for (int k = 0; k < 2; ++k) {
        float cd = cds[k], ch = chs[k], cw = cws[k];
        float d0f = floorf(cd), h0f = floorf(ch), w0f = floorf(cw);
        int d0 = (int)d0f, h0 = (int)h0f, w0 = (int)w0f;
        bool bad = (d0 < lo_d) | (d0 + 1 > hi_d)
                 | (h0 < lo_h) | (h0 + 1 > hi_h)
                 | (w0 >= W - 1);
        fb |= (int)bad << k;
        FD[k] = cd - d0f; GD[k] = 1.0f - FD[k];
        FH[k] = ch - h0f; GH[k] = 1.0f - FH[k];
        FW[k] = cw - w0f; GW[k] = 1.0f - FW[k];
        a0[k] = lds0 + (unsigned)(((d0 - lo_d) * RH + (h0 - lo_h)) * ROW_B
                                  + w0 * 8);
    }
    v4f r00[2], r01[2], r10[2], r11[2];
#pragma unroll
    for (int k = 0; k < 2; ++k) {
        unsigned a1 = a0[k] + PLANE_B;
        asm volatile("ds_read2_b64 %0, %1 offset0:0 offset1:1"
                     : "=v"(r00[k]) : "v"(a0[k]));
        asm volatile("ds_read2_b64 %0, %1 offset0:128 offset1:129"
                     : "=v"(r01[k]) : "v"(a0[k]));
        asm volatile("ds_read2_b64 %0, %1 offset0:0 offset1:1"
                     : "=v"(r10[k]) : "v"(a1));
        asm volatile("ds_read2_b64 %0, %1 offset0:128 offset1:129"
                     : "=v"(r11[k]) : "v"(a1));
    }
    asm volatile("s_waitcnt lgkmcnt(0)" ::: "memory");
    __builtin_amdgcn_sched_barrier(0);

    float acc0[2], acc1[2];
#pragma unroll
    for (int k = 0; k < 2; ++k) {
        // elements: [0]=w0c0 [1]=w0c1 [2]=w1c0 [3]=w1c1
        float p00a = r00[k][0] * GW[k] + r00[k][2] * FW[k];   // (d0,h0) ch0
        float p00b = r00[k][1] * GW[k] + r00[k][3] * FW[k];   // (d0,h0) ch1
        float p01a = r01[k][0] * GW[k] + r01[k][2] * FW[k];
        float p01b = r01[k][1] * GW[k] + r01[k][3] * FW[k];
        float p10a = r10[k][0] * GW[k] + r10[k][2] * FW[k];
        float p10b = r10[k][1] * GW[k] + r10[k][3] * FW[k];
        float p11a = r11[k][0] * GW[k] + r11[k][2] * FW[k];
        float p11b = r11[k][1] * GW[k] + r11[k][3] * FW[k];
        acc0[k] = GD[k] * (GH[k] * p00a + FH[k] * p01a)
                + FD[k] * (GH[k] * p10a + FH[k] * p11a);
        acc1[k] = GD[k] * (GH[k] * p00b + FH[k] * p01b)
                + FD[k] * (GH[k] * p10b + FH[k] * p11b);
    }
    if (fb) {                                // rare: exact global recompute
#pragma unroll
        for (int k = 0; k < 2; ++k) {
            if (fb & (1 << k)) {
                float cd = cds[k], ch = chs[k], cw = cws[k];
                float d0f = floorf(cd), h0f = floorf(ch), w0f = floorf(cw);
                float fd = cd - d0f, fh = ch - h0f, fw = cw - w0f;
                int d0 = (int)d0f, h0 = (int)h0f, w0 = (int)w0f;
                int d1 = min(d0 + 1, D - 1);
                int h1 = min(h0 + 1, H - 1);
                int w1 = min(w0 + 1, W - 1);
                float gd = 1.0f - fd, gh = 1.0f - fh, gw = 1.0f - fw;
                float w00 = gh * gw, w01 = gh * fw, w10 = fh * gw, w11 = fh * fw;
                int o00 = d0 * HW + h0 * W, o01 = d0 * HW + h1 * W;
                int o10 = d1 * HW + h0 * W, o11 = d1 * HW + h1 * W;
#pragma unroll
                for (int c = 0; c < 2; ++c) {
                    const float* gimg = imgb + c * DHW;
                    float q0 = gimg[o00 + w0] * w00 + gimg[o00 + w1] * w01
                             + gimg[o01 + w0] * w10 + gimg[o01 + w1] * w11;
                    float q1 = gimg[o10 + w0] * w00 + gimg[o10 + w1] * w01
                             + gimg[o11 + w0] * w10 + gimg[o11 + w1] * w11;
                    float v = gd * q0 + fd * q1;
                    if (c == 0) acc0[k] = v; else acc1[k] = v;
                }
            }
        }
    }

    float* outb = out + (size_t)b * C * DHW;
    *reinterpret_cast<float2*>(outb + sidx)       = make_float2(acc0[0], acc0[1]);
    *reinterpret_cast<float2*>(outb + DHW + sidx) = make_float2(acc1[0], acc1[1]);
}

extern "C" void kernel_launch(void* const* d_in, const int* in_sizes, int n_in,
                              void* d_out, int out_size, void* d_ws, size_t ws_size,
                              hipStream_t stream) {
    const float* image = (const float*)d_in[0];
    const float* ddf   = (const float*)d_in[1];
    float* out = (float*)d_out;

    int grid = B * 1024;   // 32x32 tiles of 4x4x128 per batch = 2048 blocks
    stn_kernel<<<grid, NT, 0, stream>>>(image, ddf, out);
}

// Round 19
// 37.642 us; speedup vs baseline: 1.6122x; 1.2430x over previous
//
#include <hip/hip_runtime.h>

// STN forward, R19: max-TLP small blocks. 256 threads, tile 4x4x32,
// LDS 20,480 B/block -> up to 7 blocks/CU co-resident; sequential blocks
// stagger -> stage/gather latencies hide across blocks (the resource every
// 47us-flat variant lacked). Two single-channel passes over one buffer;
// staging = exactly 5 uniform global_load_lds rounds (rows padded to 128,
// zero staging VGPRs); gather = 4x ds_read2_b32 per voxel per channel,
// batched, one lgkmcnt(0)+sched_barrier(0).

constexpr int B = 2, C = 2, D = 128, H = 128, W = 128;
constexpr int HW  = H * W;
constexpr int DHW = D * HW;
constexpr int RDH = 11;                      // d,h region extents (halo 3)
constexpr int RWD = 40;                      // w extent: tile 32, halo -4/+4
constexpr int NROW = RDH * RDH;              // 121 real rows
constexpr int NROW_P = 128;                  // padded rows (uniform staging)
constexpr int LDSF = NROW_P * RWD;           // 5120 floats = 20,480 B
constexpr int NG = LDSF / 4;                 // 1280 granules = 5 * 256
constexpr int NT = 256;
constexpr int ROW_B = RWD * 4;               // 160 B per row
constexpr int PLANE_B = RDH * ROW_B;         // 1760 B per d-plane

typedef float v2f __attribute__((ext_vector_type(2)));

__device__ __forceinline__ void gload_lds16(const float* g, float* l) {
    __builtin_amdgcn_global_load_lds(
        (const __attribute__((address_space(1))) void*)g,
        (__attribute__((address_space(3))) void*)l, 16, 0, 0);
}

__global__ __launch_bounds__(NT) void stn_kernel(
    const float* __restrict__ image,
    const float* __restrict__ ddf,
    float* __restrict__ out)
{
    __shared__ float smem[LDSF];             // 20,480 B

    // XCD-contiguous swizzle (8192 blocks, %8==0 -> bijective)
    const int bid = blockIdx.x;
    const int cpx = gridDim.x >> 3;          // 1024
    const int blk = (bid & 7) * cpx + (bid >> 3);

    const int b   = blk >> 12;               // 4096 tiles/batch: 32d x 32h x 4w
    const int tb  = blk & 4095;
    const int t0d = (tb >> 7) * 4;
    const int t0h = ((tb >> 2) & 31) * 4;
    const int t0w = (tb & 3) * 32;
    const int lo_d = max(t0d - 3, 0), lo_h = max(t0h - 3, 0);
    const int lo_w = max(t0w - 4, 0);        // 4-aligned
    const int hi_d = min(lo_d + RDH - 1, D - 1);
    const int hi_h = min(lo_h + RDH - 1, H - 1);
    const int hi_w = min(lo_w + RWD - 1, W - 1);
    const float* imgb = image + (size_t)b * C * DHW;
    const int tid = threadIdx.x;
    const unsigned lds0 =
        (unsigned)(uintptr_t)(__attribute__((address_space(3))) void*)&smem[0];

    // 2 voxels/thread: (d_, h_, w2) and (d_, h_, w2+1)
    const int dd = tid >> 6, hh = (tid >> 4) & 3, wi = tid & 15;
    const int d_ = t0d + dd, h_ = t0h + hh;
    const int w2 = t0w + wi * 2;
    const int sidx = d_ * HW + h_ * W + w2;

    // ---- ddf loads FIRST ----
    const float* dp = ddf + (size_t)b * 3 * DHW;
    float2 vd = *reinterpret_cast<const float2*>(dp + sidx);
    float2 vh = *reinterpret_cast<const float2*>(dp + DHW + sidx);
    float2 vw = *reinterpret_cast<const float2*>(dp + 2 * DHW + sidx);
    asm volatile("" ::: "memory");

    // granule g -> global offset (rows >120 and w-overhang duplicate, never read)
    auto gsrc_off = [&](int g) {
        int row = g / 10;                    // 10 granules per 40-dword row
        int rw  = (g - row * 10) * 4;
        int rc  = min(row, NROW - 1);
        int rd  = rc / RDH;
        int rh  = rc - rd * RDH;
        return min(lo_d + rd, D - 1) * HW + min(lo_h + rh, H - 1) * W
             + min(lo_w + rw, W - 4);
    };

    auto issue_stage = [&](const float* src) {
#pragma unroll
        for (int i = 0; i < 5; ++i) {        // 5 * 256 = 1280, no tail
            int g = tid + i * NT;
            gload_lds16(src + gsrc_off(g), &smem[g * 4]);
        }
    };

    issue_stage(imgb);                       // ch0 in flight
    asm volatile("" ::: "memory");

    // clamped coords (persisted across both passes; 6 VGPR)
    float cds[2], chs[2], cws[2];
    cds[0] = fminf(fmaxf((float)d_ + vd.x, 0.0f), (float)(D - 1));
    cds[1] = fminf(fmaxf((float)d_ + vd.y, 0.0f), (float)(D - 1));
    chs[0] = fminf(fmaxf((float)h_ + vh.x, 0.0f), (float)(H - 1));
    chs[1] = fminf(fmaxf((float)h_ + vh.y, 0.0f), (float)(H - 1));
    cws[0] = fminf(fmaxf((float)w2 + vw.x, 0.0f), (float)(W - 1));
    cws[1] = fminf(fmaxf((float)(w2 + 1) + vw.y, 0.0f), (float)(W - 1));

    // one pass: 8 ds_read2_b32 batched -> one wait -> FMAs; rare fixup; f2 store
    auto do_pass = [&](const float* gimg, float* optr) {
        unsigned a0[2];
        float W00[2], W01[2], W10[2], W11[2], GD[2], FD[2];
        int fb = 0;
#pragma unroll
        for (int k = 0; k < 2; ++k) {
            float cd = cds[k], ch = chs[k], cw = cws[k];
            float d0f = floorf(cd), h0f = floorf(ch), w0f = floorf(cw);
            float fd = cd - d0f, fh = ch - h0f, fw = cw - w0f;
            int d0 = (int)d0f, h0 = (int)h0f, w0 = (int)w0f;
            bool bad = (d0 < lo_d) | (d0 + 1 > hi_d)
                     | (h0 < lo_h) | (h0 + 1 > hi_h)
                     | (w0 < lo_w) | (w0 + 1 > hi_w);
            fb |= (int)bad << k;
            float gh = 1.0f - fh, gw = 1.0f - fw;
            W00[k] = gh * gw; W01[k] = gh * fw;
            W10[k] = fh * gw; W11[k] = fh * fw;
            GD[k] = 1.0f - fd; FD[k] = fd;
            int row = (d0 - lo_d) * RDH + (h0 - lo_h);
            a0[k] = lds0 + (unsigned)(row * ROW_B + (w0 - lo_w) * 4);
        }
        v2f r00[2], r01[2], r10[2], r11[2];
#pragma unroll
        for (int k = 0; k < 2; ++k) {
            unsigned a1 = a0[k] + PLANE_B;
            asm volatile("ds_read2_b32 %0, %1 offset0:0 offset1:1"
                         : "=v"(r00[k]) : "v"(a0[k]));
            asm volatile("ds_read2_b32 %0, %1 offset0:40 offset1:41"
                         : "=v"(r01[k]) : "v"(a0[k]));
            asm volatile("ds_read2_b32 %0, %1 offset0:0 offset1:1"
                         : "=v"(r10[k]) : "v"(a1));
            asm volatile("ds_read2_b32 %0, %1 offset0:40 offset1:41"
                         : "=v"(r11[k]) : "v"(a1));
        }
        asm volatile("s_waitcnt lgkmcnt(0)" ::: "memory");
        __builtin_amdgcn_sched_barrier(0);

        float acc[2];
#pragma unroll
        for (int k = 0; k < 2; ++k) {
            float p0 = r00[k].x * W00[k] + r00[k].y * W01[k]
                     + r01[k].x * W10[k] + r01[k].y * W11[k];
            float p1 = r10[k].x * W00[k] + r10[k].y * W01[k]
                     + r11[k].x * W10[k] + r11[k].y * W11[k];
            acc[k] = GD[k] * p0 + FD[k] * p1;
        }
        if (fb) {                            // rare: exact global recompute
#pragma unroll
            for (int k = 0; k < 2; ++k) {
                if (fb & (1 << k)) {
                    float cd = cds[k], ch = chs[k], cw = cws[k];
                    float d0f = floorf(cd), h0f = floorf(ch), w0f = floorf(cw);
                    float fd = cd - d0f, fh = ch - h0f, fw = cw - w0f;
                    int d0 = (int)d0f, h0 = (int)h0f, w0 = (int)w0f;
                    int d1 = min(d0 + 1, D - 1);
                    int h1 = min(h0 + 1, H - 1);
                    int w1 = min(w0 + 1, W - 1);
                    float gd = 1.0f - fd, gh = 1.0f - fh, gw = 1.0f - fw;
                    float w00 = gh * gw, w01 = gh * fw, w10 = fh * gw, w11 = fh * fw;
                    int o00 = d0 * HW + h0 * W, o01 = d0 * HW + h1 * W;
                    int o10 = d1 * HW + h0 * W, o11 = d1 * HW + h1 * W;
                    float q0 = gimg[o00 + w0] * w00 + gimg[o00 + w1] * w01
                             + gimg[o01 + w0] * w10 + gimg[o01 + w1] * w11;
                    float q1 = gimg[o10 + w0] * w00 + gimg[o10 + w1] * w01
                             + gimg[o11 + w0] * w10 + gimg[o11 + w1] * w11;
                    acc[k] = gd * q0 + fd * q1;
                }
            }
        }
        *reinterpret_cast<float2*>(optr) = make_float2(acc[0], acc[1]);
    };

    float* outb = out + (size_t)b * C * DHW;

    // ---- pass 0 ----
    asm volatile("s_waitcnt vmcnt(0)" ::: "memory");    // ch0 staged
    __builtin_amdgcn_s_barrier();
    do_pass(imgb, outb + sidx);

    __builtin_amdgcn_s_barrier();                       // ch0 reads done
    asm volatile("" ::: "memory");

    // ---- pass 1 ----
    issue_stage(imgb + DHW);
    asm volatile("s_waitcnt vmcnt(0)" ::: "memory");    // ch1 staged
    __builtin_amdgcn_s_barrier();
    do_pass(imgb + DHW, outb + DHW + sidx);
}

extern "C" void kernel_launch(void* const* d_in, const int* in_sizes, int n_in,
                              void* d_out, int out_size, void* d_ws, size_t ws_size,
                              hipStream_t stream) {
    const float* image = (const float*)d_in[0];
    const float* ddf   = (const float*)d_in[1];
    float* out = (float*)d_out;

    int grid = B * 4096;   // 32d x 32h x 4w tiles of 4x4x32 = 8192 blocks
    stn_kernel<<<grid, NT, 0, stream>>>(image, ddf, out);
}